// Round 8
// baseline (662.548 us; speedup 1.0000x reference)
//
#include <hip/hip_runtime.h>
#include <hip/hip_bf16.h>

#define NN 10000
#define NE 100000
#define NCH 5000                 // node chunk for P (bounds workspace to ~85 MB)

typedef __bf16   bf16x8 __attribute__((ext_vector_type(8)));
typedef _Float16 f16x8  __attribute__((ext_vector_type(8)));
typedef _Float16 f16x2  __attribute__((ext_vector_type(2)));
typedef float    f32x4  __attribute__((ext_vector_type(4)));

__device__ __forceinline__ f32x4 relu4(f32x4 a) {
    a.x = fmaxf(a.x, 0.f); a.y = fmaxf(a.y, 0.f);
    a.z = fmaxf(a.z, 0.f); a.w = fmaxf(a.w, 0.f);
    return a;
}

__device__ __forceinline__ float fdot2h(f16x2 a, f16x2 b, float c) {
#if defined(__has_builtin)
#if __has_builtin(__builtin_amdgcn_fdot2)
    return __builtin_amdgcn_fdot2(a, b, c, false);
#else
    return c + (float)a.x * (float)b.x + (float)a.y * (float)b.y;
#endif
#else
    return c + (float)a.x * (float)b.x + (float)a.y * (float)b.y;
#endif
}

// ---------------- one-time kernels ----------------

__global__ void k_deg(const int* __restrict__ eidx, int* __restrict__ deg_r,
                      int* __restrict__ deg_c) {
    int e = blockIdx.x * blockDim.x + threadIdx.x;
    if (e < NE) {
        atomicAdd(&deg_r[eidx[e]], 1);
        atomicAdd(&deg_c[eidx[NE + e]], 1);
    }
}

// blockIdx.x==0: row scan; ==1: col scan. Exclusive prefix -> ptr[NN+1], cursor.
__global__ void k_scan(const int* __restrict__ degA, int* __restrict__ ptrA, int* __restrict__ curA,
                       const int* __restrict__ degB, int* __restrict__ ptrB, int* __restrict__ curB) {
    const int* deg = blockIdx.x ? degB : degA;
    int* ptr = blockIdx.x ? ptrB : ptrA;
    int* cur = blockIdx.x ? curB : curA;
    __shared__ int ssum[256];
    const int tid = threadIdx.x;
    const int CH = 40;
    const int base = tid * CH;
    int s = 0;
    for (int i = 0; i < CH; ++i) { int n = base + i; if (n < NN) s += deg[n]; }
    ssum[tid] = s;
    __syncthreads();
    for (int off = 1; off < 256; off <<= 1) {
        int t = (tid >= off) ? ssum[tid - off] : 0;
        __syncthreads();
        ssum[tid] += t;
        __syncthreads();
    }
    int run = ssum[tid] - s;
    for (int i = 0; i < CH; ++i) {
        int n = base + i;
        if (n < NN) { ptr[n] = run; cur[n] = run; run += deg[n]; }
    }
    if (tid == 255) ptr[NN] = ssum[255];
}

__global__ void k_fill(const int* __restrict__ eidx, int* __restrict__ cur_r,
                       int* __restrict__ cur_c, int* __restrict__ ebyrow,
                       int* __restrict__ ebycol) {
    int e = blockIdx.x * blockDim.x + threadIdx.x;
    if (e < NE) {
        int sr = atomicAdd(&cur_r[eidx[e]], 1);
        ebyrow[sr] = e;
        int sc = atomicAdd(&cur_c[eidx[NE + e]], 1);
        ebycol[sc] = e;
    }
}

__global__ void k_init(const float* __restrict__ x, const float* __restrict__ fc1w,
                       const float* __restrict__ fc1b, const float* __restrict__ cinit,
                       const int* __restrict__ deg,
                       float* __restrict__ h, float* __restrict__ coord,
                       float* __restrict__ deg_inv) {
    int n = blockIdx.x * blockDim.x + threadIdx.x;
    if (n >= NN) return;
    float x0 = x[n*3+0], x1 = x[n*3+1], x2 = x[n*3+2];
    #pragma unroll
    for (int j = 0; j < 32; j += 4) {
        f32x4 a = *(const f32x4*)(fc1b + j);
        a += x0 * (*(const f32x4*)(fc1w + 0*32 + j));
        a += x1 * (*(const f32x4*)(fc1w + 1*32 + j));
        a += x2 * (*(const f32x4*)(fc1w + 2*32 + j));
        *(f32x4*)(h + n*32 + j) = a;   // no relu on fc1 (matches reference)
    }
    coord[n*3+0] = cinit[n*3+0];
    coord[n*3+1] = cinit[n*3+1];
    coord[n*3+2] = cinit[n*3+2];
    int d = deg[n];
    deg_inv[n] = 1.0f / (float)(d > 1 ? d : 1);
}

// Build Bsw: B-frag layout fp16 of W3''[j][c], c=k2*64+i*2+s (4160 cols, K=32 j),
// rows 128=b3, 129=0. Also w2sw (bf16 B-frag of ker_w2, for k_edge12).
__global__ void k_wsw(const float* __restrict__ w3, const float* __restrict__ b3,
                      _Float16* __restrict__ Bsw,
                      const float* __restrict__ w2, __bf16* __restrict__ w2sw) {
    int t = blockIdx.x * blockDim.x + threadIdx.x;
    if (t < 133120) {                        // 260 nt-tiles x 512
        int jj = t & 7;
        int L  = (t >> 3) & 63;
        int nt = t >> 9;
        int j  = (L >> 4)*8 + jj;            // K index 0..31
        int c  = nt*16 + (L & 15);           // col 0..4159
        int k2 = c >> 6, rr = c & 63;
        int i = rr >> 1, s = rr & 1;
        int kidx = 2*k2 + s;
        float v = (kidx < 128) ? w3[kidx*1024 + i*32 + j]
                               : (s == 0 ? b3[i*32 + j] : 0.0f);
        Bsw[t] = (_Float16)v;
    } else if (t < 133120 + 8192) {
        int u = t - 133120;
        int jj = u & 7;
        int L  = (u >> 3) & 63;
        int ks = (u >> 9) & 1;
        int nt = u >> 10;
        int c1 = ks*32 + (L >> 4)*8 + jj;
        int c2 = nt*16 + (L & 15);
        w2sw[u] = (__bf16)w2[c1*128 + c2];
    }
}

// ---------------- per-layer kernels ----------------

// Fused edge MLP: coord_diff/radial -> layer1 (per-lane, 64ch in regs) ->
// XOR-swizzled per-wave LDS tile -> A-frags -> layer2 MFMA -> kbf [E,128] fp16.
__global__ __launch_bounds__(256, 2)
void k_edge12(const float* __restrict__ coord, const int* __restrict__ eidx,
              const float* __restrict__ eattr,
              const float* __restrict__ w1, const float* __restrict__ b1,
              const __bf16* __restrict__ w2sw, const float* __restrict__ b2,
              float* __restrict__ cd4, _Float16* __restrict__ kbf) {
    __shared__ __bf16 ktile[4][4096];
    const int tid = threadIdx.x;
    const int wave = tid >> 6, lane = tid & 63;
    const int q = lane >> 4, t = lane & 15;
    const int e = blockIdx.x * 256 + tid;
    const int ec = e < NE ? e : NE - 1;
    const int wbase = blockIdx.x * 256 + wave * 64;
    __bf16* kt = ktile[wave];

    int r = eidx[ec], c = eidx[NE + ec];
    float dx = coord[r*3+0] - coord[c*3+0];
    float dy = coord[r*3+1] - coord[c*3+1];
    float dz = coord[r*3+2] - coord[c*3+2];
    float rad = dx*dx + dy*dy + dz*dz;
    if (e < NE) {
        f32x4 cdv = {dx, dy, dz, rad};
        *(f32x4*)(cd4 + (size_t)e*4) = cdv;
    }
    float kin[7];
    #pragma unroll
    for (int a = 0; a < 6; ++a) kin[a] = eattr[(size_t)ec*6 + a];
    kin[6] = rad;

    f32x4 acc1[16];
    #pragma unroll
    for (int g = 0; g < 16; ++g) acc1[g] = *(const f32x4*)(b1 + g*4);
    #pragma unroll
    for (int t7 = 0; t7 < 7; ++t7) {
        float kv = kin[t7];
        #pragma unroll
        for (int g = 0; g < 16; ++g)
            acc1[g] += kv * (*(const f32x4*)(w1 + t7*64 + g*4));
    }
    #pragma unroll
    for (int cc = 0; cc < 8; ++cc) {
        f32x4 a0 = relu4(acc1[cc*2]), a1 = relu4(acc1[cc*2+1]);
        bf16x8 pk = {(__bf16)a0.x, (__bf16)a0.y, (__bf16)a0.z, (__bf16)a0.w,
                     (__bf16)a1.x, (__bf16)a1.y, (__bf16)a1.z, (__bf16)a1.w};
        *(bf16x8*)(kt + lane*64 + ((cc ^ (lane & 7)) * 8)) = pk;
    }
    __syncthreads();

    bf16x8 af[4][2];
    #pragma unroll
    for (int mt = 0; mt < 4; ++mt) {
        int ep = mt*16 + t;
        #pragma unroll
        for (int ks = 0; ks < 2; ++ks)
            af[mt][ks] = *(const bf16x8*)(kt + ep*64 + (((ks*4 + q) ^ (ep & 7)) * 8));
    }

    for (int nt = 0; nt < 8; ++nt) {
        f32x4 a2[4];
        #pragma unroll
        for (int mt = 0; mt < 4; ++mt) a2[mt] = (f32x4){0.f, 0.f, 0.f, 0.f};
        #pragma unroll
        for (int ks = 0; ks < 2; ++ks) {
            bf16x8 bf_ = *(const bf16x8*)(w2sw + ((nt*2 + ks)*64 + lane) * 8);
            #pragma unroll
            for (int mt = 0; mt < 4; ++mt)
                a2[mt] = __builtin_amdgcn_mfma_f32_16x16x32_bf16(af[mt][ks], bf_, a2[mt], 0, 0, 0);
        }
        float bias = b2[nt*16 + t];
        #pragma unroll
        for (int mt = 0; mt < 4; ++mt) {
            #pragma unroll
            for (int rr = 0; rr < 4; ++rr) {
                int e2 = wbase + mt*16 + q*4 + rr;
                if (e2 < NE)
                    kbf[(size_t)e2*128 + nt*16 + t] = (_Float16)fmaxf(a2[mt][rr] + bias, 0.f);
            }
        }
    }
}

// Node GEMM: P[n][k2][i][s] = sum_j W3''[j][c] * h[n][j]  (c=k2*64+i*2+s, 4160 cols)
// MFMA f16, 1 wave/block over 64 nodes, grid.y splits the 130 nt-pairs (5 per wave).
// LDS transpose -> coalesced 64B row stores of P fp16.
__global__ __launch_bounds__(64, 4)
void k_pmat(const float* __restrict__ h, const _Float16* __restrict__ Bsw,
            _Float16* __restrict__ P, int n0, int n1) {
    __shared__ _Float16 tile[64 * 40];       // 64 nodes x 32 cols, stride 40 (16B-aligned rows)
    const int lane = threadIdx.x;
    const int q = lane >> 4, t = lane & 15;
    const int nbase = n0 + blockIdx.x * 64;

    f16x8 af[4];
    #pragma unroll
    for (int mt = 0; mt < 4; ++mt) {
        int node = nbase + mt*16 + t;
        node = node < NN ? node : NN - 1;
        const float* hp = h + (size_t)node*32 + q*8;
        f32x4 h0 = *(const f32x4*)(hp);
        f32x4 h1 = *(const f32x4*)(hp + 4);
        af[mt] = (f16x8){(_Float16)h0.x, (_Float16)h0.y, (_Float16)h0.z, (_Float16)h0.w,
                         (_Float16)h1.x, (_Float16)h1.y, (_Float16)h1.z, (_Float16)h1.w};
    }

    const int node_s = nbase + lane;
    const bool do_store = (node_s < n1) && (node_s < NN);
    _Float16* prow = P + (size_t)(node_s - n0) * 4160;

    for (int w = 0; w < 5; ++w) {
        int pidx = blockIdx.y * 5 + w;        // 0..129
        #pragma unroll
        for (int hf = 0; hf < 2; ++hf) {
            int nt = pidx*2 + hf;
            f16x8 bf_ = *(const f16x8*)(Bsw + nt*512 + lane*8);
            #pragma unroll
            for (int mt = 0; mt < 4; ++mt) {
                f32x4 acc = (f32x4){0.f, 0.f, 0.f, 0.f};
                acc = __builtin_amdgcn_mfma_f32_16x16x32_f16(af[mt], bf_, acc, 0, 0, 0);
                #pragma unroll
                for (int rr = 0; rr < 4; ++rr)
                    tile[(mt*16 + q*4 + rr)*40 + hf*16 + t] = (_Float16)acc[rr];
            }
        }
        if (do_store) {
            const f16x8* tr = (const f16x8*)(tile + lane*40);
            f16x8 v0 = tr[0], v1 = tr[1], v2 = tr[2], v3 = tr[3];
            _Float16* dst = prow + pidx*32;
            *(f16x8*)(dst)      = v0;
            *(f16x8*)(dst + 8)  = v1;
            *(f16x8*)(dst + 16) = v2;
            *(f16x8*)(dst + 24) = v3;
        }
    }
}

// Edge contraction in col-sorted order: m[e][i] = sum_k2 dot2(kk2[k2], P2[n][k2][i])
// + bias-row, then phi MLP, plain stores. Thread = sorted edge slot.
__global__ __launch_bounds__(256, 2)
void k_msg(const _Float16* __restrict__ kbf, const _Float16* __restrict__ P,
           const int* __restrict__ colptr, const int* __restrict__ ebycol,
           const int* __restrict__ eidx,
           const float* __restrict__ cm_w1, const float* __restrict__ cm_b1,
           const float* __restrict__ cm_w2,
           float* __restrict__ m_t, float* __restrict__ phiv, int n0, int n1) {
    const int p0 = colptr[n0], p1 = colptr[n1];
    const int p = p0 + blockIdx.x * 256 + threadIdx.x;
    if (p >= p1) return;
    const int e = ebycol[p];
    const int n = eidx[NE + e];

    f16x8 kv[16];
    const f16x8* kkp = (const f16x8*)(kbf + (size_t)e * 128);
    #pragma unroll
    for (int v = 0; v < 16; ++v) kv[v] = kkp[v];

    float acc[32];
    #pragma unroll
    for (int i = 0; i < 32; ++i) acc[i] = 0.f;

    const f16x8* pbase = (const f16x8*)(P + (size_t)(n - n0) * 4160);
    #pragma unroll 2
    for (int k2 = 0; k2 < 64; ++k2) {
        f16x8 pv[8];
        #pragma unroll
        for (int v = 0; v < 8; ++v) pv[v] = pbase[k2*8 + v];
        f16x2 ka = (f16x2){kv[k2 >> 2][(k2 & 3)*2], kv[k2 >> 2][(k2 & 3)*2 + 1]};
        #pragma unroll
        for (int i = 0; i < 32; ++i) {
            f16x2 pa = (f16x2){pv[i >> 2][(i & 3)*2], pv[i >> 2][(i & 3)*2 + 1]};
            acc[i] = fdot2h(ka, pa, acc[i]);
        }
    }
    {   // bias row (k2 = 64, kk = (1,0))
        f16x8 pv[8];
        #pragma unroll
        for (int v = 0; v < 8; ++v) pv[v] = pbase[64*8 + v];
        #pragma unroll
        for (int i = 0; i < 32; ++i)
            acc[i] += (float)pv[i >> 2][(i & 3)*2];
    }

    // store m
    #pragma unroll
    for (int o = 0; o < 32; o += 4) {
        f32x4 mv = {acc[o], acc[o+1], acc[o+2], acc[o+3]};
        *(f32x4*)(m_t + (size_t)e*32 + o) = mv;
    }

    // phi MLP (32 -> 32 relu -> 1)
    float phi = 0.f;
    for (int o = 0; o < 32; o += 4) {
        f32x4 a = *(const f32x4*)(cm_b1 + o);
        #pragma unroll
        for (int i = 0; i < 32; ++i)
            a += acc[i] * (*(const f32x4*)(cm_w1 + i*32 + o));
        a = relu4(a);
        f32x4 w2 = *(const f32x4*)(cm_w2 + o);
        phi += a.x*w2.x + a.y*w2.y + a.z*w2.z + a.w*w2.w;
    }
    phiv[e] = phi;
}

// CSR gather: 8 threads per node.
__global__ __launch_bounds__(256, 4)
void k_gather(const int* __restrict__ rowptr, const int* __restrict__ ebyrow,
              const float* __restrict__ m_t, const float* __restrict__ phiv,
              const float* __restrict__ cd4, const float* __restrict__ deg_inv,
              float* __restrict__ coord, float* __restrict__ h) {
    int tid = blockIdx.x * blockDim.x + threadIdx.x;
    int n = tid >> 3, sub = tid & 7;
    if (n >= NN) return;
    int st = rowptr[n], en = rowptr[n+1];
    f32x4 am = {0.f, 0.f, 0.f, 0.f};
    float cx = 0.f, cy = 0.f, cz = 0.f;
    for (int p = st; p < en; ++p) {
        int e = ebyrow[p];
        am += *(const f32x4*)(m_t + (size_t)e*32 + sub*4);
        if (sub == 0) {
            f32x4 cd = *(const f32x4*)(cd4 + (size_t)e*4);
            float ph = phiv[e];
            cx += cd.x * ph; cy += cd.y * ph; cz += cd.z * ph;
        }
    }
    float di = deg_inv[n];
    f32x4 hv = *(const f32x4*)(h + (size_t)n*32 + sub*4);
    hv = relu4(hv + am * di);
    *(f32x4*)(h + (size_t)n*32 + sub*4) = hv;
    if (sub == 0) {
        coord[n*3+0] += cx * di;
        coord[n*3+1] += cy * di;
        coord[n*3+2] += cz * di;
    }
}

__global__ __launch_bounds__(256, 4)
void k_final(const float* __restrict__ h, const float* __restrict__ coord,
             const float* __restrict__ fw1, const float* __restrict__ fb1,
             const float* __restrict__ fw2, const float* __restrict__ fb2,
             float* __restrict__ out) {
    int n = blockIdx.x * blockDim.x + threadIdx.x;
    if (n >= NN) return;
    float hreg[32];
    #pragma unroll
    for (int i = 0; i < 32; ++i) hreg[i] = h[n*32 + i];
    float ov = fb2[0];
    for (int o = 0; o < 64; o += 4) {
        f32x4 a = *(const f32x4*)(fb1 + o);
        #pragma unroll
        for (int i = 0; i < 32; ++i)
            a += hreg[i] * (*(const f32x4*)(fw1 + i*64 + o));
        a = relu4(a);
        f32x4 w2 = *(const f32x4*)(fw2 + o);
        ov += a.x*w2.x + a.y*w2.y + a.z*w2.z + a.w*w2.w;
    }
    out[n] = ov;
    out[NN + n*3 + 0] = coord[n*3+0];
    out[NN + n*3 + 1] = coord[n*3+1];
    out[NN + n*3 + 2] = coord[n*3+2];
}

// ---------------- launch ----------------

extern "C" void kernel_launch(void* const* d_in, const int* in_sizes, int n_in,
                              void* d_out, int out_size, void* d_ws, size_t ws_size,
                              hipStream_t stream) {
    const float* x      = (const float*)d_in[0];
    const int*   eidx   = (const int*)  d_in[1];
    const float* eattr  = (const float*)d_in[2];
    const float* cinit  = (const float*)d_in[3];
    const float* fc1w   = (const float*)d_in[4];
    const float* fc1b   = (const float*)d_in[5];
    const float* kw1    = (const float*)d_in[6];
    const float* kb1    = (const float*)d_in[7];
    const float* kw2    = (const float*)d_in[8];
    const float* kb2    = (const float*)d_in[9];
    const float* kw3    = (const float*)d_in[10];
    const float* kb3    = (const float*)d_in[11];
    const float* cmw1   = (const float*)d_in[12];
    const float* cmb1   = (const float*)d_in[13];
    const float* cmw2   = (const float*)d_in[14];
    const float* f2w1   = (const float*)d_in[15];
    const float* f2b1   = (const float*)d_in[16];
    const float* f2w2   = (const float*)d_in[17];
    const float* f2b2   = (const float*)d_in[18];
    float* out = (float*)d_out;

    char* p = (char*)d_ws;
    auto carve = [&](size_t bytes) {
        void* r = (void*)p;
        p += (bytes + 255) & ~(size_t)255;
        return r;
    };
    float*     h        = (float*)    carve((size_t)NN * 32 * 4);
    float*     coord    = (float*)    carve((size_t)NN * 3 * 4);
    int*       degs     = (int*)      carve((size_t)2 * NN * 4);  // [deg_r | deg_c]
    float*     deg_inv  = (float*)    carve((size_t)NN * 4);
    int*       rowptr   = (int*)      carve((size_t)(NN + 1) * 4);
    int*       colptr   = (int*)      carve((size_t)(NN + 1) * 4);
    int*       cur_r    = (int*)      carve((size_t)NN * 4);
    int*       cur_c    = (int*)      carve((size_t)NN * 4);
    int*       ebyrow   = (int*)      carve((size_t)NE * 4);
    int*       ebycol   = (int*)      carve((size_t)NE * 4);
    float*     cd4      = (float*)    carve((size_t)NE * 4 * 4);
    float*     m_t      = (float*)    carve((size_t)NE * 32 * 4);
    float*     phiv     = (float*)    carve((size_t)NE * 4);
    _Float16*  kbf      = (_Float16*) carve((size_t)NE * 128 * 2);
    _Float16*  Bsw      = (_Float16*) carve((size_t)133120 * 2);
    __bf16*    w2sw     = (__bf16*)   carve((size_t)8192 * 2);
    _Float16*  Pbuf     = (_Float16*) carve((size_t)NCH * 4160 * 2);  // 41.6 MB
    int* deg_r = degs;
    int* deg_c = degs + NN;

    const int TB = 256;
    dim3 gE((NE + TB - 1) / TB), gN((NN + TB - 1) / TB), b(TB);
    dim3 gA((NN*8 + TB - 1) / TB);
    dim3 gP((NCH + 63) / 64, 26);            // 79 node-groups x 26 pair-chunks

    hipMemsetAsync(degs, 0, (size_t)2 * NN * 4, stream);
    k_deg <<<gE, b, 0, stream>>>(eidx, deg_r, deg_c);
    k_scan<<<2, b, 0, stream>>>(deg_r, rowptr, cur_r, deg_c, colptr, cur_c);
    k_fill<<<gE, b, 0, stream>>>(eidx, cur_r, cur_c, ebyrow, ebycol);
    k_init<<<gN, b, 0, stream>>>(x, fc1w, fc1b, cinit, deg_r, h, coord, deg_inv);
    k_wsw <<<552, b, 0, stream>>>(kw3, kb3, Bsw, kw2, w2sw);

    for (int d = 0; d < 3; ++d) {
        k_edge12<<<gE, b, 0, stream>>>(coord, eidx, eattr, kw1, kb1, w2sw, kb2, cd4, kbf);
        for (int ch = 0; ch < 2; ++ch) {
            int n0 = ch * NCH, n1 = (ch + 1) * NCH;
            k_pmat<<<gP, dim3(64), 0, stream>>>(h, Bsw, Pbuf, n0, n1);
            k_msg <<<gE, b, 0, stream>>>(kbf, Pbuf, colptr, ebycol, eidx,
                                         cmw1, cmb1, cmw2, m_t, phiv, n0, n1);
        }
        k_gather<<<gA, b, 0, stream>>>(rowptr, ebyrow, m_t, phiv, cd4, deg_inv, coord, h);
    }
    k_final<<<gN, b, 0, stream>>>(h, coord, f2w1, f2b1, f2w2, f2b2, out);
}